// Round 14
// baseline (461.953 us; speedup 1.0000x reference)
//
#include <hip/hip_runtime.h>

typedef _Float16 f16;
typedef _Float16 f16x8 __attribute__((ext_vector_type(8)));
typedef float f32x4 __attribute__((ext_vector_type(4)));

#define N_BOX 1805
#define NPIX 361
#define NCLS 20
#define GNW 29            // ceil(1805/64) mask words per row
#define MB_ROWS 226       // ceil(1805/8) rows per maskbuild block

__device__ __forceinline__ float leakyf(float x){ return x > 0.f ? x : 0.1f*x; }
__device__ __forceinline__ float sigmoidf_(float x){ return 1.f/(1.f + expf(-x)); }

// ---------------- small transpose: dst[C][R] = src[R][C] (fp32, for wrT/wpT) ----------------
__global__ void transpose_k(const float* __restrict__ src, float* __restrict__ dst, int R, int C){
  int i = blockIdx.x*256 + threadIdx.x;
  if (i < R*C){ int r = i / C, c = i % C; dst[c*R + r] = src[i]; }
}

// ---------------- weight prep (GATHER): fp32 w[Cout][Cin][9] -> frag-order A tiles (16KB) ----
__global__ void wprep10_k(const float* __restrict__ w, f16* __restrict__ wpk,
                          int Cin, int cpt, int NK, int total){
  int gid = blockIdx.x*256 + threadIdx.x;      // over 8*NK*512
  if (gid >= total) return;
  int m    = gid & 3;
  int lane = (gid >> 2) & 63;
  int wr   = (gid >> 8) & 1;
  int tile = gid >> 9;
  int kc   = tile % NK;
  int cob  = tile / NK;
  int t    = kc / cpt;
  int ciblk = kc - t*cpt;
  int lrow = lane & 15, jci = lane >> 4;
  int row = wr*64 + m*16 + lrow;
  int co  = cob*128 + row;
  int ci0 = ciblk*32 + jci*8;
  const float* src = w + ((size_t)co*Cin + ci0)*9 + t;
  f16x8 hv, lv;
  #pragma unroll
  for (int k = 0; k < 8; ++k){
    float f = src[(size_t)k*9] * 64.f;
    f16 hi = (f16)f;
    hv[k] = hi;
    lv[k] = (f16)(f - (float)hi);
  }
  f16x8* dst = (f16x8*)wpk + (size_t)tile*1024 + (size_t)(wr*64 + lane)*8;
  dst[m]     = hv;
  dst[4 + m] = lv;
}

// ---------------- act1 prep: feat3[1024][361] fp32 -> a1hi/a1lo[361][1024] f16 ----------------
__global__ void act1prep_k(const float* __restrict__ feat3, f16* __restrict__ ah, f16* __restrict__ al){
  int i = blockIdx.x*256 + threadIdx.x;  // over 361*1024
  if (i >= NPIX*1024) return;
  int p = i >> 10, c = i & 1023;
  float v = feat3[c*NPIX + p];
  f16 hi = (f16)v; f16 lo = (f16)(v - (float)hi);
  ah[i] = hi; al[i] = lo;
}

// ---------------- reorg path: leaky(conv1x1(feat2, wr)+br) -> reorg -> cat[ ][0:256) f16 hi/lo ----------------
__global__ __launch_bounds__(256) void reorg_conv_k(const float* __restrict__ feat2,
    const float* __restrict__ wrT, const float* __restrict__ br,
    f16* __restrict__ cath, f16* __restrict__ catl){
  int c  = threadIdx.x & 63;
  int pq = threadIdx.x >> 6;
  int pix = blockIdx.x*4 + pq;      // 0..1443
  int y = pix / 38, x = pix % 38;
  __shared__ float s_in[64][4];
  float acc = br[c];
  for (int cb = 0; cb < 512; cb += 64){
    __syncthreads();
    { int k = threadIdx.x >> 2, pp = threadIdx.x & 3;
      s_in[k][pp] = feat2[(cb + k)*1444 + blockIdx.x*4 + pp]; }
    __syncthreads();
    #pragma unroll
    for (int k = 0; k < 64; ++k)
      acc = fmaf(wrT[(cb+k)*64 + c], s_in[k][pq], acc);
  }
  float v = leakyf(acc);
  int co = ((y & 1)*2 + (x & 1))*64 + c;   // reorg channel mapping
  int p = (y>>1)*19 + (x>>1);
  f16 hi = (f16)v; f16 lo = (f16)(v - (float)hi);
  size_t o = (size_t)p*1280 + co;
  cath[o] = hi; catl[o] = lo;
}

// ---------------- 3x3 conv as MFMA GEMM (f16 2-term split, 3 passes), split-K partials ----------------
// A: DIRECT global->register, DOUBLE-BUFFERED (prefetch chunk i+1 during MFMA of chunk i).
// B: LDS double-buffered reg-staged with halo masking (1 barrier/chunk).
__global__ __launch_bounds__(256) void conv_mfma_k(
    const f16* __restrict__ wpk,
    const f16* __restrict__ ahi, const f16* __restrict__ alo,
    float* __restrict__ part, int Cin, int chunks, int cpt, int NK)
{
  int cob = blockIdx.x;                // 0..7
  int px0 = blockIdx.y * 128;
  int ks  = blockIdx.z;
  int kc0 = ks * chunks;
  int tid = threadIdx.x;

  __shared__ f16 sB[2][128*64];        // 2 x 16KB

  int lane = tid & 63, wid = tid >> 6;
  int lrow = lane & 15, lgrp = lane >> 4;
  int wr = wid >> 1, wc = wid & 1;

  // A: direct fragment pointer (per chunk advance by 1024 f16x8)
  const f16x8* abase = (const f16x8*)wpk + (size_t)(cob*NK + kc0)*1024 + (size_t)(wr*64 + lane)*8;

  // B staging mapping: thread covers 4 rows (srow + s*32), fixed slot
  int srow = tid >> 3;
  int sdata = (tid & 7) ^ (srow & 7);
  int sh = sdata >> 2, sjci = sdata & 3;
  const f16* bbase = sh ? alo : ahi;
  int spy[4], spx[4]; bool spv[4];
  #pragma unroll
  for (int s = 0; s < 4; ++s){
    int p = px0 + srow + s*32;
    spv[s] = (p < NPIX);
    int pc = spv[s] ? p : 0;
    spy[s] = pc / 19; spx[s] = pc - spy[s]*19;
  }

  // B fragment read offsets (bytes)
  int boffH[4], boffL[4];
  #pragma unroll
  for (int n = 0; n < 4; ++n){
    int rB = wc*64 + n*16 + lrow;
    boffH[n] = (rB*128 + lgrp*16)     ^ ((rB & 7) << 4);
    boffL[n] = (rB*128 + (4+lgrp)*16) ^ ((rB & 7) << 4);
  }

  f32x4 acc[4][4] = {};
  f16x8 bs0, bs1, bs2, bs3;
  f16x8 A0[8], A1[8];                  // [0..3]=hi m, [4..7]=lo m (static indexing only)

  auto LOADB = [&](int i){
    int kc = kc0 + i;
    int t = kc / cpt;
    int ci0 = (kc - t*cpt) * 32;
    int dy = t/3, dx = t - dy*3;
    f16x8 z = {};
    bs0 = z; bs1 = z; bs2 = z; bs3 = z;
    #pragma unroll
    for (int s = 0; s < 4; ++s){
      int yy = spy[s] + dy - 1, xx = spx[s] + dx - 1;
      bool ok = spv[s] & ((unsigned)yy < 19u) & ((unsigned)xx < 19u);
      if (ok){
        f16x8 vv = *(const f16x8*)(bbase + (size_t)(yy*19+xx)*Cin + ci0 + sjci*8);
        if (s == 0) bs0 = vv; else if (s == 1) bs1 = vv; else if (s == 2) bs2 = vv; else bs3 = vv;
      }
    }
  };
  auto WRITEB = [&](int buf){
    *(f16x8*)(&sB[buf][(tid +   0)*8]) = bs0;
    *(f16x8*)(&sB[buf][(tid + 256)*8]) = bs1;
    *(f16x8*)(&sB[buf][(tid + 512)*8]) = bs2;
    *(f16x8*)(&sB[buf][(tid + 768)*8]) = bs3;
  };
  auto LOADA0 = [&](int i){
    const f16x8* ap = abase + (size_t)i*1024;
    #pragma unroll
    for (int m = 0; m < 8; ++m) A0[m] = ap[m];
  };
  auto LOADA1 = [&](int i){
    const f16x8* ap = abase + (size_t)i*1024;
    #pragma unroll
    for (int m = 0; m < 8; ++m) A1[m] = ap[m];
  };

  LOADB(0);
  LOADA0(0);
  WRITEB(0);
  __syncthreads();

  for (int i = 0; i < chunks; i += 2){
    { // even step: compute with A0 / sB[0], prefetch chunk i+1 into A1 / sB[1]
      bool more = (i + 1 < chunks);
      if (more){ LOADB(i + 1); LOADA1(i + 1); }
      f16x8 bh[4], bl[4];
      #pragma unroll
      for (int n = 0; n < 4; ++n){
        bh[n] = *(const f16x8*)((char*)sB[0] + boffH[n]);
        bl[n] = *(const f16x8*)((char*)sB[0] + boffL[n]);
      }
      #pragma unroll
      for (int m = 0; m < 4; ++m){
        #pragma unroll
        for (int n = 0; n < 4; ++n){
          acc[m][n] = __builtin_amdgcn_mfma_f32_16x16x32_f16(A0[m],   bh[n], acc[m][n], 0,0,0);
          acc[m][n] = __builtin_amdgcn_mfma_f32_16x16x32_f16(A0[m],   bl[n], acc[m][n], 0,0,0);
          acc[m][n] = __builtin_amdgcn_mfma_f32_16x16x32_f16(A0[4+m], bh[n], acc[m][n], 0,0,0);
        }
      }
      if (more) WRITEB(1);
      __syncthreads();
    }
    if (i + 1 < chunks){ // odd step: compute with A1 / sB[1], prefetch chunk i+2 into A0 / sB[0]
      bool more = (i + 2 < chunks);
      if (more){ LOADB(i + 2); LOADA0(i + 2); }
      f16x8 bh[4], bl[4];
      #pragma unroll
      for (int n = 0; n < 4; ++n){
        bh[n] = *(const f16x8*)((char*)sB[1] + boffH[n]);
        bl[n] = *(const f16x8*)((char*)sB[1] + boffL[n]);
      }
      #pragma unroll
      for (int m = 0; m < 4; ++m){
        #pragma unroll
        for (int n = 0; n < 4; ++n){
          acc[m][n] = __builtin_amdgcn_mfma_f32_16x16x32_f16(A1[m],   bh[n], acc[m][n], 0,0,0);
          acc[m][n] = __builtin_amdgcn_mfma_f32_16x16x32_f16(A1[m],   bl[n], acc[m][n], 0,0,0);
          acc[m][n] = __builtin_amdgcn_mfma_f32_16x16x32_f16(A1[4+m], bh[n], acc[m][n], 0,0,0);
        }
      }
      if (more) WRITEB(0);
      __syncthreads();
    }
  }

  #pragma unroll
  for (int m = 0; m < 4; ++m){
    #pragma unroll
    for (int n = 0; n < 4; ++n){
      int pp = px0 + wc*64 + n*16 + lrow;
      if (pp < NPIX){
        int co = cob*128 + wr*64 + m*16 + lgrp*4;
        size_t base = ((size_t)ks*1024 + co)*NPIX + pp;
        part[base          ] = acc[m][n][0];
        part[base +   NPIX ] = acc[m][n][1];
        part[base + 2*NPIX ] = acc[m][n][2];
        part[base + 3*NPIX ] = acc[m][n][3];
      }
    }
  }
}

// ---------------- reduce split-K partials (x1/64) + bias + leaky -> transposed f16 hi/lo ----------------
__global__ void reduce16v_k(const float* __restrict__ part, const float* __restrict__ bias,
                            f16* __restrict__ dhi, f16* __restrict__ dlo,
                            int Cstride, int Coff, int splitk){
  int i = blockIdx.x*256 + threadIdx.x;
  if (i >= 1024*NPIX) return;
  int co = i / NPIX, p = i - co*NPIX;
  float s = 0.f;
  for (int k = 0; k < splitk; ++k) s += part[(size_t)k*1024*NPIX + i];
  float v = leakyf(s*0.015625f + bias[co]);
  f16 hi = (f16)v;
  f16 lo = (f16)(v - (float)hi);
  size_t o = (size_t)p*Cstride + Coff + co;
  dhi[o] = hi; dlo[o] = lo;
}

// ---------------- pred 1x1 conv: act3[361][1024] (hi+lo) -> 125 ----------------
__global__ __launch_bounds__(256) void pred_conv_k(const f16* __restrict__ a3h, const f16* __restrict__ a3l,
    const float* __restrict__ wpT, const float* __restrict__ bp, float* __restrict__ pred){
  int c = threadIdx.x & 127, ph = threadIdx.x >> 7;
  int pix = blockIdx.x*2 + ph;
  __shared__ float s_in[64][2];
  float acc = 0.f;
  for (int cb = 0; cb < 1024; cb += 64){
    __syncthreads();
    if (threadIdx.x < 128){
      int k = threadIdx.x & 63, pp = threadIdx.x >> 6;
      int px2 = blockIdx.x*2 + pp;
      float v = 0.f;
      if (px2 < NPIX){
        size_t o = (size_t)px2*1024 + cb + k;
        v = (float)a3h[o] + (float)a3l[o];
      }
      s_in[k][pp] = v;
    }
    __syncthreads();
    if (c < 125){
      #pragma unroll
      for (int k = 0; k < 64; ++k)
        acc = fmaf(wpT[(cb+k)*125 + c], s_in[k][ph], acc);
    }
  }
  if (c < 125 && pix < NPIX) pred[c*NPIX + pix] = acc + bp[c];
}

// ---------------- decode boxes / scores / argmax (+ zero class counters) ----------------
__device__ const float ANCW[5] = {1.19f, 2.79f, 4.53f, 8.06f, 10.32f};
__device__ const float ANCH_[5] = {1.98f, 4.59f, 8.92f, 5.29f, 10.65f};

__global__ void decode_k(const float* __restrict__ pred, float* __restrict__ out,
                         int* __restrict__ cls_i, int* __restrict__ cnt){
  int n = blockIdx.x*256 + threadIdx.x;
  if (blockIdx.x == 0 && threadIdx.x < NCLS) cnt[threadIdx.x] = 0;
  if (n >= N_BOX) return;
  int p = n / 5, a = n % 5;
  float conf = pred[a*NPIX + p];
  float cl[20]; float m = -1e30f;
  #pragma unroll
  for (int k = 0; k < 20; ++k){ cl[k] = pred[(5 + a*20 + k)*NPIX + p]; m = fmaxf(m, cl[k]); }
  float s = 0.f;
  #pragma unroll
  for (int k = 0; k < 20; ++k){ cl[k] = expf(cl[k]-m); s += cl[k]; }
  int bi = 0; float bv = cl[0];
  #pragma unroll
  for (int k = 1; k < 20; ++k) if (cl[k] > bv){ bv = cl[k]; bi = k; }
  float score = sigmoidf_(conf) * (bv / s);
  float tx = pred[(105 + a*4 + 0)*NPIX + p];
  float ty = pred[(105 + a*4 + 1)*NPIX + p];
  float tw = pred[(105 + a*4 + 2)*NPIX + p];
  float th = pred[(105 + a*4 + 3)*NPIX + p];
  float gx = (float)(p % 19), gy = (float)(p / 19);
  float cx = (sigmoidf_(tx) + gx) * 32.f;
  float cy = (sigmoidf_(ty) + gy) * 32.f;
  float bw = expf(tw) * ANCW[a] * 32.f;
  float bh = expf(th) * ANCH_[a] * 32.f;
  float x1 = fminf(fmaxf((cx - 0.5f*bw) / 608.f, 0.f), 1.f);
  float y1 = fminf(fmaxf((cy - 0.5f*bh) / 608.f, 0.f), 1.f);
  float x2 = fminf(fmaxf((cx + 0.5f*bw) / 608.f, 0.f), 1.f);
  float y2 = fminf(fmaxf((cy + 0.5f*bh) / 608.f, 0.f), 1.f);
  out[n*4+0]=x1; out[n*4+1]=y1; out[n*4+2]=x2; out[n*4+3]=y2;
  out[7220 + n]  = score;
  out[9025 + n]  = (float)bi;
  out[10830 + n] = 0.f;          // keep init
  cls_i[n] = bi;
}

// ---------------- per-class rank, wave-parallel (1 wave per box) ----------------
__global__ __launch_bounds__(256) void rank_k(const float* __restrict__ scores,
    const int* __restrict__ cls_i, int* __restrict__ ord, int* __restrict__ cnt){
  __shared__ float s_sc[N_BOX];
  __shared__ short s_cl[N_BOX];
  int tid = threadIdx.x;
  for (int j = tid; j < N_BOX; j += 256){ s_sc[j] = scores[j]; s_cl[j] = (short)cls_i[j]; }
  __syncthreads();
  int wid = tid >> 6, lane = tid & 63;
  int i = blockIdx.x*4 + wid;
  if (i >= N_BOX) return;
  float si = s_sc[i]; short ci = s_cl[i];
  int r = 0;
  for (int j = lane; j < N_BOX; j += 64){
    float sj = s_sc[j];
    r += (int)((s_cl[j] == ci) & ((sj > si) | ((sj == si) & (j < i))));
  }
  #pragma unroll
  for (int o = 32; o; o >>= 1) r += __shfl_down(r, o);
  if (lane == 0){
    ord[ci*N_BOX + r] = i;
    atomicAdd(&cnt[ci], 1);
  }
}

// ---------------- NMS phase A: parallel suppression-mask build ----------------
__global__ __launch_bounds__(256) void maskbuild_k(const float* __restrict__ boxes,
    const int* __restrict__ ord, const int* __restrict__ cnt,
    unsigned long long* __restrict__ gmask){
  __shared__ float X1[N_BOX], Y1[N_BOX], X2[N_BOX], Y2[N_BOX], AR[N_BOX];
  int c = blockIdx.x, chunk = blockIdx.y, tid = threadIdx.x;
  int n = cnt[c];
  int r0 = chunk*MB_ROWS;
  if (n <= 0 || r0 >= n) return;
  int r1 = r0 + MB_ROWS; if (r1 > n) r1 = n;
  int rows_here = r1 - r0;
  for (int t = tid; t < n; t += 256){
    int bi = ord[c*N_BOX + t];
    float x1 = boxes[bi*4+0], y1 = boxes[bi*4+1], x2 = boxes[bi*4+2], y2 = boxes[bi*4+3];
    X1[t]=x1; Y1[t]=y1; X2[t]=x2; Y2[t]=y2; AR[t]=(x2-x1)*(y2-y1);
  }
  __syncthreads();
  int nw = (n + 63) >> 6;
  unsigned long long* rows = gmask + (size_t)c*N_BOX*GNW;
  for (int task = tid; task < rows_here*nw; task += 256){
    int w = task / rows_here, ri = task - w*rows_here;
    int i = r0 + ri;
    float ax1=X1[i], ay1=Y1[i], ax2=X2[i], ay2=Y2[i], areaA=AR[i];
    unsigned long long bits = 0;
    int j0 = w << 6;
    int jb = i+1 > j0 ? i+1 : j0;
    int je = j0+64 < n ? j0+64 : n;
    for (int j = jb; j < je; ++j){
      float iw = fmaxf(1e-10f, fminf(ax2,X2[j]) - fmaxf(ax1,X1[j]));
      float ih = fmaxf(1e-10f, fminf(ay2,Y2[j]) - fmaxf(ay1,Y1[j]));
      float inter = iw*ih;
      float iou = inter / (areaA + AR[j] - inter);
      bits |= (unsigned long long)(iou > 0.5f) << (j - j0);
    }
    rows[(size_t)i*GNW + w] = bits;
  }
}

// ---------------- NMS phase B: word-centric greedy scan, 1 wave per class ----------------
__global__ __launch_bounds__(64) void nmsscan_k(const int* __restrict__ ord,
    const int* __restrict__ cnt, const unsigned long long* __restrict__ gmask,
    float* __restrict__ keep){
  __shared__ int sidx[N_BOX];
  int c = blockIdx.x, lane = threadIdx.x;
  int n = cnt[c];
  if (n <= 0) return;
  int nw = (n + 63) >> 6;
  for (int t = lane; t < n; t += 64) sidx[t] = ord[c*N_BOX + t];
  __syncthreads();
  const unsigned long long* rows = gmask + (size_t)c*N_BOX*GNW;
  bool act = lane < nw;
  unsigned long long S = 0;
  unsigned long long diag = (lane < n) ? rows[(size_t)lane*GNW + 0] : 0ull;
  for (int w = 0; w < nw; ++w){
    int base = w << 6;
    int nb = n - base; if (nb > 64) nb = 64;
    unsigned int slo = (unsigned)__builtin_amdgcn_readlane((int)(unsigned)S, w);
    unsigned int shi = (unsigned)__builtin_amdgcn_readlane((int)(unsigned)(S >> 32), w);
    unsigned long long sup = ((unsigned long long)shi << 32) | slo;
    unsigned long long validm = (nb >= 64) ? ~0ull : ((1ull << nb) - 1ull);
    unsigned long long avail = ~sup & validm;
    unsigned long long kmask = 0;
    unsigned long long diag_next = 0;
    if (w+1 < nw){
      int i2 = base + 64 + lane;
      if (i2 < n) diag_next = rows[(size_t)i2*GNW + (w+1)];
    }
    while (avail){
      int b = __builtin_ctzll(avail);
      kmask |= 1ull << b;
      unsigned int dlo = (unsigned)__builtin_amdgcn_readlane((int)(unsigned)diag, b);
      unsigned int dhi = (unsigned)__builtin_amdgcn_readlane((int)(unsigned)(diag >> 32), b);
      unsigned long long drow = ((unsigned long long)dhi << 32) | dlo;
      sup |= drow;
      avail &= ~(1ull << b);
      avail &= ~sup;
      if (act && lane > w)
        S |= rows[(size_t)(base + b)*GNW + lane];
    }
    if ((kmask >> lane) & 1ull) keep[sidx[base + lane]] = 1.f;
    diag = diag_next;
  }
}

static inline size_t align256(size_t x){ return (x + 255) & ~(size_t)255; }

extern "C" void kernel_launch(void* const* d_in, const int* in_sizes, int n_in,
                              void* d_out, int out_size, void* d_ws, size_t ws_size,
                              hipStream_t stream){
  const float* feat2 = (const float*)d_in[0];   // (512,38,38)
  const float* feat3 = (const float*)d_in[1];   // (1024,19,19)
  const float* w1a = (const float*)d_in[2];
  const float* b1a = (const float*)d_in[3];
  const float* w1b = (const float*)d_in[4];
  const float* b1b = (const float*)d_in[5];
  const float* wr  = (const float*)d_in[6];
  const float* br  = (const float*)d_in[7];
  const float* w2  = (const float*)d_in[8];
  const float* b2  = (const float*)d_in[9];
  const float* wp  = (const float*)d_in[10];
  const float* bp  = (const float*)d_in[11];
  float* out = (float*)d_out;
  char* ws = (char*)d_ws;

  size_t off = 0;
  float* part = (float*)(ws + off); off = align256(off + (size_t)24*1024*NPIX*4);
  f16* wpk  = (f16*)(ws + off); off = align256(off + (size_t)8*360*8192*2);   // 47.2MB: 8x360 tiles x 16KB
  f16* a1h  = (f16*)(ws + off); off = align256(off + (size_t)NPIX*1024*2);
  f16* a1l  = (f16*)(ws + off); off = align256(off + (size_t)NPIX*1024*2);
  f16* a2h  = (f16*)(ws + off); off = align256(off + (size_t)NPIX*1024*2);
  f16* a2l  = (f16*)(ws + off); off = align256(off + (size_t)NPIX*1024*2);
  f16* a3h  = (f16*)(ws + off); off = align256(off + (size_t)NPIX*1024*2);
  f16* a3l  = (f16*)(ws + off); off = align256(off + (size_t)NPIX*1024*2);
  f16* cath = (f16*)(ws + off); off = align256(off + (size_t)NPIX*1280*2);
  f16* catl = (f16*)(ws + off); off = align256(off + (size_t)NPIX*1280*2);
  float* pred = (float*)(ws + off); off = align256(off + (size_t)125*NPIX*4);
  float* wrT  = (float*)(ws + off); off = align256(off + (size_t)512*64*4);
  float* wpT  = (float*)(ws + off); off = align256(off + (size_t)1024*125*4);
  int* cls_i  = (int*)(ws + off); off = align256(off + (size_t)N_BOX*4);
  int* ord    = (int*)(ws + off); off = align256(off + (size_t)NCLS*N_BOX*4);
  int* cnt    = (int*)(ws + off); off = align256(off + (size_t)NCLS*4);
  unsigned long long* gmask = (unsigned long long*)part;   // part free by NMS time

  transpose_k<<<(64*512 + 255)/256, 256, 0, stream>>>(wr, wrT, 64, 512);
  transpose_k<<<(125*1024 + 255)/256, 256, 0, stream>>>(wp, wpT, 125, 1024);
  act1prep_k<<<(NPIX*1024 + 255)/256, 256, 0, stream>>>(feat3, a1h, a1l);
  reorg_conv_k<<<361, 256, 0, stream>>>(feat2, wrT, br, cath, catl);

  // conv1: act1 (Cin=1024, NK=288, cpt=32): splitk 24 x chunks 12 -> 576 blocks
  wprep10_k<<<(8*288*512 + 255)/256, 256, 0, stream>>>(w1a, wpk, 1024, 32, 288, 8*288*512);
  { dim3 g(8, 3, 24);
    conv_mfma_k<<<g, 256, 0, stream>>>(wpk, a1h, a1l, part, 1024, 12, 32, 288); }
  reduce16v_k<<<(1024*NPIX + 255)/256, 256, 0, stream>>>(part, b1a, a2h, a2l, 1024, 0, 24);

  // conv2: act2 -> cat[256:1280)
  wprep10_k<<<(8*288*512 + 255)/256, 256, 0, stream>>>(w1b, wpk, 1024, 32, 288, 8*288*512);
  { dim3 g(8, 3, 24);
    conv_mfma_k<<<g, 256, 0, stream>>>(wpk, a2h, a2l, part, 1024, 12, 32, 288); }
  reduce16v_k<<<(1024*NPIX + 255)/256, 256, 0, stream>>>(part, b1b, cath, catl, 1280, 256, 24);

  // conv3: cat (Cin=1280, NK=360, cpt=40): splitk 24 x chunks 15 -> 576 blocks
  wprep10_k<<<(8*360*512 + 255)/256, 256, 0, stream>>>(w2, wpk, 1280, 40, 360, 8*360*512);
  { dim3 g(8, 3, 24);
    conv_mfma_k<<<g, 256, 0, stream>>>(wpk, cath, catl, part, 1280, 15, 40, 360); }
  reduce16v_k<<<(1024*NPIX + 255)/256, 256, 0, stream>>>(part, b2, a3h, a3l, 1024, 0, 24);

  // pred 1x1 + decode + NMS
  pred_conv_k<<<181, 256, 0, stream>>>(a3h, a3l, wpT, bp, pred);
  decode_k<<<8, 256, 0, stream>>>(pred, out, cls_i, cnt);
  rank_k<<<(N_BOX + 3)/4, 256, 0, stream>>>(out + 7220, cls_i, ord, cnt);
  { dim3 mg(NCLS, 8);
    maskbuild_k<<<mg, 256, 0, stream>>>(out, ord, cnt, gmask); }
  nmsscan_k<<<NCLS, 64, 0, stream>>>(ord, cnt, gmask, out + 10830);
}

// Round 15
// 321.595 us; speedup vs baseline: 1.4364x; 1.4364x over previous
//
#include <hip/hip_runtime.h>

typedef _Float16 f16;
typedef _Float16 f16x8 __attribute__((ext_vector_type(8)));
typedef float f32x4 __attribute__((ext_vector_type(4)));

#define N_BOX 1805
#define NPIX 361
#define NCLS 20
#define GNW 29            // ceil(1805/64) mask words per row
#define MB_ROWS 226       // ceil(1805/8) rows per maskbuild block

__device__ __forceinline__ float leakyf(float x){ return x > 0.f ? x : 0.1f*x; }
__device__ __forceinline__ float sigmoidf_(float x){ return 1.f/(1.f + expf(-x)); }

// async global->LDS, 16B per lane; LDS dest must be wave-uniform base + lane*16 (linear)
__device__ __forceinline__ void gl16(const f16* g, f16* l){
  __builtin_amdgcn_global_load_lds(
      (const __attribute__((address_space(1))) unsigned int*)g,
      (__attribute__((address_space(3))) unsigned int*)l, 16, 0, 0);
}

// ---------------- small transpose: dst[C][R] = src[R][C] (fp32, for wrT/wpT) ----------------
__global__ void transpose_k(const float* __restrict__ src, float* __restrict__ dst, int R, int C){
  int i = blockIdx.x*256 + threadIdx.x;
  if (i < R*C){ int r = i / C, c = i % C; dst[c*R + r] = src[i]; }
}

// ---------------- weight prep (gather, coalesced): fp32 w[Cout][Cin][9] -> R9-layout tiles ----
// Tile (cob,kc) = 16KB: 128 rows x 8 slots x 16B. Stored slot s of row r holds data
// sdata = s ^ (r&7): h=sdata>>2 (0=hi,1=lo), jci=sdata&3 -> split(w[co][ci0+jci*8..+8][t]*64).
// One thread per 16B slot; consecutive gid -> consecutive 16B writes (full lines, no RMW).
__global__ void wprep11_k(const float* __restrict__ w, f16* __restrict__ wpk,
                          int Cin, int cpt, int NK, int total){
  int gid = blockIdx.x*256 + threadIdx.x;      // over 8*NK*1024
  if (gid >= total) return;
  int g    = gid & 1023;
  int tile = gid >> 10;
  int kc   = tile % NK;
  int cob  = tile / NK;
  int row  = g >> 3, sraw = g & 7;
  int sdata = sraw ^ (row & 7);
  int h = sdata >> 2, jci = sdata & 3;
  int t = kc / cpt;
  int ciblk = kc - t*cpt;
  int ci0 = ciblk*32 + jci*8;
  int co = cob*128 + row;
  const float* src = w + ((size_t)co*Cin + ci0)*9 + t;
  f16x8 outv;
  #pragma unroll
  for (int k = 0; k < 8; ++k){
    float f = src[(size_t)k*9] * 64.f;
    f16 hi = (f16)f;
    outv[k] = h ? (f16)(f - (float)hi) : hi;
  }
  *((f16x8*)wpk + gid) = outv;
}

// ---------------- act1 prep: feat3[1024][361] fp32 -> a1hi/a1lo[361][1024] f16 (+ zero page) --
__global__ void act1prep_k(const float* __restrict__ feat3, f16* __restrict__ ah, f16* __restrict__ al,
                           f16* __restrict__ zpage){
  int i = blockIdx.x*256 + threadIdx.x;  // over 361*1024
  if (blockIdx.x == 0 && threadIdx.x < 64) zpage[threadIdx.x] = (f16)0.f;
  if (i >= NPIX*1024) return;
  int p = i >> 10, c = i & 1023;
  float v = feat3[c*NPIX + p];
  f16 hi = (f16)v; f16 lo = (f16)(v - (float)hi);
  ah[i] = hi; al[i] = lo;
}

// ---------------- reorg path: leaky(conv1x1(feat2, wr)+br) -> reorg -> cat[ ][0:256) f16 hi/lo ----------------
__global__ __launch_bounds__(256) void reorg_conv_k(const float* __restrict__ feat2,
    const float* __restrict__ wrT, const float* __restrict__ br,
    f16* __restrict__ cath, f16* __restrict__ catl){
  int c  = threadIdx.x & 63;
  int pq = threadIdx.x >> 6;
  int pix = blockIdx.x*4 + pq;      // 0..1443
  int y = pix / 38, x = pix % 38;
  __shared__ float s_in[64][4];
  float acc = br[c];
  for (int cb = 0; cb < 512; cb += 64){
    __syncthreads();
    { int k = threadIdx.x >> 2, pp = threadIdx.x & 3;
      s_in[k][pp] = feat2[(cb + k)*1444 + blockIdx.x*4 + pp]; }
    __syncthreads();
    #pragma unroll
    for (int k = 0; k < 64; ++k)
      acc = fmaf(wrT[(cb+k)*64 + c], s_in[k][pq], acc);
  }
  float v = leakyf(acc);
  int co = ((y & 1)*2 + (x & 1))*64 + c;   // reorg channel mapping
  int p = (y>>1)*19 + (x>>1);
  f16 hi = (f16)v; f16 lo = (f16)(v - (float)hi);
  size_t o = (size_t)p*1280 + co;
  cath[o] = hi; catl[o] = lo;
}

// ---------------- 3x3 conv as MFMA GEMM (f16 2-term split, 3 passes), split-K partials ----------------
// A and B both staged via global_load_lds (16B/lane, linear LDS dest, swizzle baked into
// the GLOBAL layout/source address). Double-buffered, 1 barrier per chunk. Zero ds_write.
__global__ __launch_bounds__(256) void conv_mfma_k(
    const f16* __restrict__ wpk,
    const f16* __restrict__ ahi, const f16* __restrict__ alo,
    const f16* __restrict__ zpage,
    float* __restrict__ part, int Cin, int chunks, int cpt, int NK)
{
  int cob = blockIdx.x;                // 0..7
  int px0 = blockIdx.y * 128;
  int ks  = blockIdx.z;
  int kc0 = ks * chunks;
  int tid = threadIdx.x;

  __shared__ f16 sA[2][8192];          // 2 x 16KB
  __shared__ f16 sB[2][8192];          // 2 x 16KB

  int lane = tid & 63, wid = tid >> 6;
  int lrow = lane & 15, lgrp = lane >> 4;
  int wr = wid >> 1, wc = wid & 1;

  const f16* wtile0 = wpk + (size_t)(cob*NK + kc0)*8192;

  // B source geometry: thread covers rows (srow + s*32), fixed (sh, sjci) slot
  int srow = tid >> 3;
  int sdata = (tid & 7) ^ (srow & 7);
  int sh = sdata >> 2, sjci = sdata & 3;
  const f16* bbase = sh ? alo : ahi;
  int spy[4], spx[4]; bool spv[4];
  #pragma unroll
  for (int s = 0; s < 4; ++s){
    int p = px0 + srow + s*32;
    spv[s] = (p < NPIX);
    int pc = spv[s] ? p : 0;
    spy[s] = pc / 19; spx[s] = pc - spy[s]*19;
  }

  // fragment read offsets (bytes, XOR matches global pre-swizzle)
  int aoffH[4], aoffL[4], boffH[4], boffL[4];
  #pragma unroll
  for (int m = 0; m < 4; ++m){
    int rA = wr*64 + m*16 + lrow;
    aoffH[m] = (rA*128 + lgrp*16)     ^ ((rA & 7) << 4);
    aoffL[m] = (rA*128 + (4+lgrp)*16) ^ ((rA & 7) << 4);
    int rB = wc*64 + m*16 + lrow;
    boffH[m] = (rB*128 + lgrp*16)     ^ ((rB & 7) << 4);
    boffL[m] = (rB*128 + (4+lgrp)*16) ^ ((rB & 7) << 4);
  }

  f32x4 acc[4][4] = {};

  auto ISSUE = [&](int i, int buf){
    const f16* wt = wtile0 + (size_t)i*8192;
    #pragma unroll
    for (int j = 0; j < 4; ++j){
      int o = (tid + j*256)*8;
      gl16(wt + o, &sA[buf][o]);
    }
    int kc = kc0 + i;
    int t = kc / cpt;
    int ci0 = (kc - t*cpt) * 32;
    int dy = t/3, dx = t - dy*3;
    #pragma unroll
    for (int s = 0; s < 4; ++s){
      int yy = spy[s] + dy - 1, xx = spx[s] + dx - 1;
      bool ok = spv[s] & ((unsigned)yy < 19u) & ((unsigned)xx < 19u);
      const f16* src = ok ? (bbase + (size_t)(yy*19+xx)*Cin + ci0 + sjci*8) : zpage;
      gl16(src, &sB[buf][(tid + s*256)*8]);
    }
  };

  ISSUE(0, 0);
  __syncthreads();                      // drains vmcnt -> buf 0 ready

  for (int i = 0; i < chunks; ++i){
    int cur = i & 1;
    if (i + 1 < chunks) ISSUE(i + 1, cur ^ 1);   // loads fly during MFMA below

    f16x8 bh[4], bl[4];
    #pragma unroll
    for (int n = 0; n < 4; ++n){
      bh[n] = *(const f16x8*)((char*)sB[cur] + boffH[n]);
      bl[n] = *(const f16x8*)((char*)sB[cur] + boffL[n]);
    }
    #pragma unroll
    for (int m = 0; m < 4; ++m){
      f16x8 ah = *(const f16x8*)((char*)sA[cur] + aoffH[m]);
      f16x8 al = *(const f16x8*)((char*)sA[cur] + aoffL[m]);
      #pragma unroll
      for (int n = 0; n < 4; ++n){
        acc[m][n] = __builtin_amdgcn_mfma_f32_16x16x32_f16(ah, bh[n], acc[m][n], 0,0,0);
        acc[m][n] = __builtin_amdgcn_mfma_f32_16x16x32_f16(ah, bl[n], acc[m][n], 0,0,0);
        acc[m][n] = __builtin_amdgcn_mfma_f32_16x16x32_f16(al, bh[n], acc[m][n], 0,0,0);
      }
    }
    __syncthreads();                    // drains prefetch into cur^1 + protects reuse of cur
  }

  #pragma unroll
  for (int m = 0; m < 4; ++m){
    #pragma unroll
    for (int n = 0; n < 4; ++n){
      int pp = px0 + wc*64 + n*16 + lrow;
      if (pp < NPIX){
        int co = cob*128 + wr*64 + m*16 + lgrp*4;
        size_t base = ((size_t)ks*1024 + co)*NPIX + pp;
        part[base          ] = acc[m][n][0];
        part[base +   NPIX ] = acc[m][n][1];
        part[base + 2*NPIX ] = acc[m][n][2];
        part[base + 3*NPIX ] = acc[m][n][3];
      }
    }
  }
}

// ---------------- reduce split-K partials (x1/64) + bias + leaky -> transposed f16 hi/lo ----------------
__global__ void reduce16v_k(const float* __restrict__ part, const float* __restrict__ bias,
                            f16* __restrict__ dhi, f16* __restrict__ dlo,
                            int Cstride, int Coff, int splitk){
  int i = blockIdx.x*256 + threadIdx.x;
  if (i >= 1024*NPIX) return;
  int co = i / NPIX, p = i - co*NPIX;
  float s = 0.f;
  for (int k = 0; k < splitk; ++k) s += part[(size_t)k*1024*NPIX + i];
  float v = leakyf(s*0.015625f + bias[co]);
  f16 hi = (f16)v;
  f16 lo = (f16)(v - (float)hi);
  size_t o = (size_t)p*Cstride + Coff + co;
  dhi[o] = hi; dlo[o] = lo;
}

// ---------------- pred 1x1 conv: act3[361][1024] (hi+lo) -> 125 ----------------
__global__ __launch_bounds__(256) void pred_conv_k(const f16* __restrict__ a3h, const f16* __restrict__ a3l,
    const float* __restrict__ wpT, const float* __restrict__ bp, float* __restrict__ pred){
  int c = threadIdx.x & 127, ph = threadIdx.x >> 7;
  int pix = blockIdx.x*2 + ph;
  __shared__ float s_in[64][2];
  float acc = 0.f;
  for (int cb = 0; cb < 1024; cb += 64){
    __syncthreads();
    if (threadIdx.x < 128){
      int k = threadIdx.x & 63, pp = threadIdx.x >> 6;
      int px2 = blockIdx.x*2 + pp;
      float v = 0.f;
      if (px2 < NPIX){
        size_t o = (size_t)px2*1024 + cb + k;
        v = (float)a3h[o] + (float)a3l[o];
      }
      s_in[k][pp] = v;
    }
    __syncthreads();
    if (c < 125){
      #pragma unroll
      for (int k = 0; k < 64; ++k)
        acc = fmaf(wpT[(cb+k)*125 + c], s_in[k][ph], acc);
    }
  }
  if (c < 125 && pix < NPIX) pred[c*NPIX + pix] = acc + bp[c];
}

// ---------------- decode boxes / scores / argmax (+ zero class counters) ----------------
__device__ const float ANCW[5] = {1.19f, 2.79f, 4.53f, 8.06f, 10.32f};
__device__ const float ANCH_[5] = {1.98f, 4.59f, 8.92f, 5.29f, 10.65f};

__global__ void decode_k(const float* __restrict__ pred, float* __restrict__ out,
                         int* __restrict__ cls_i, int* __restrict__ cnt){
  int n = blockIdx.x*256 + threadIdx.x;
  if (blockIdx.x == 0 && threadIdx.x < NCLS) cnt[threadIdx.x] = 0;
  if (n >= N_BOX) return;
  int p = n / 5, a = n % 5;
  float conf = pred[a*NPIX + p];
  float cl[20]; float m = -1e30f;
  #pragma unroll
  for (int k = 0; k < 20; ++k){ cl[k] = pred[(5 + a*20 + k)*NPIX + p]; m = fmaxf(m, cl[k]); }
  float s = 0.f;
  #pragma unroll
  for (int k = 0; k < 20; ++k){ cl[k] = expf(cl[k]-m); s += cl[k]; }
  int bi = 0; float bv = cl[0];
  #pragma unroll
  for (int k = 1; k < 20; ++k) if (cl[k] > bv){ bv = cl[k]; bi = k; }
  float score = sigmoidf_(conf) * (bv / s);
  float tx = pred[(105 + a*4 + 0)*NPIX + p];
  float ty = pred[(105 + a*4 + 1)*NPIX + p];
  float tw = pred[(105 + a*4 + 2)*NPIX + p];
  float th = pred[(105 + a*4 + 3)*NPIX + p];
  float gx = (float)(p % 19), gy = (float)(p / 19);
  float cx = (sigmoidf_(tx) + gx) * 32.f;
  float cy = (sigmoidf_(ty) + gy) * 32.f;
  float bw = expf(tw) * ANCW[a] * 32.f;
  float bh = expf(th) * ANCH_[a] * 32.f;
  float x1 = fminf(fmaxf((cx - 0.5f*bw) / 608.f, 0.f), 1.f);
  float y1 = fminf(fmaxf((cy - 0.5f*bh) / 608.f, 0.f), 1.f);
  float x2 = fminf(fmaxf((cx + 0.5f*bw) / 608.f, 0.f), 1.f);
  float y2 = fminf(fmaxf((cy + 0.5f*bh) / 608.f, 0.f), 1.f);
  out[n*4+0]=x1; out[n*4+1]=y1; out[n*4+2]=x2; out[n*4+3]=y2;
  out[7220 + n]  = score;
  out[9025 + n]  = (float)bi;
  out[10830 + n] = 0.f;          // keep init
  cls_i[n] = bi;
}

// ---------------- per-class rank, wave-parallel (1 wave per box) ----------------
__global__ __launch_bounds__(256) void rank_k(const float* __restrict__ scores,
    const int* __restrict__ cls_i, int* __restrict__ ord, int* __restrict__ cnt){
  __shared__ float s_sc[N_BOX];
  __shared__ short s_cl[N_BOX];
  int tid = threadIdx.x;
  for (int j = tid; j < N_BOX; j += 256){ s_sc[j] = scores[j]; s_cl[j] = (short)cls_i[j]; }
  __syncthreads();
  int wid = tid >> 6, lane = tid & 63;
  int i = blockIdx.x*4 + wid;
  if (i >= N_BOX) return;
  float si = s_sc[i]; short ci = s_cl[i];
  int r = 0;
  for (int j = lane; j < N_BOX; j += 64){
    float sj = s_sc[j];
    r += (int)((s_cl[j] == ci) & ((sj > si) | ((sj == si) & (j < i))));
  }
  #pragma unroll
  for (int o = 32; o; o >>= 1) r += __shfl_down(r, o);
  if (lane == 0){
    ord[ci*N_BOX + r] = i;
    atomicAdd(&cnt[ci], 1);
  }
}

// ---------------- NMS phase A: parallel suppression-mask build ----------------
__global__ __launch_bounds__(256) void maskbuild_k(const float* __restrict__ boxes,
    const int* __restrict__ ord, const int* __restrict__ cnt,
    unsigned long long* __restrict__ gmask){
  __shared__ float X1[N_BOX], Y1[N_BOX], X2[N_BOX], Y2[N_BOX], AR[N_BOX];
  int c = blockIdx.x, chunk = blockIdx.y, tid = threadIdx.x;
  int n = cnt[c];
  int r0 = chunk*MB_ROWS;
  if (n <= 0 || r0 >= n) return;
  int r1 = r0 + MB_ROWS; if (r1 > n) r1 = n;
  int rows_here = r1 - r0;
  for (int t = tid; t < n; t += 256){
    int bi = ord[c*N_BOX + t];
    float x1 = boxes[bi*4+0], y1 = boxes[bi*4+1], x2 = boxes[bi*4+2], y2 = boxes[bi*4+3];
    X1[t]=x1; Y1[t]=y1; X2[t]=x2; Y2[t]=y2; AR[t]=(x2-x1)*(y2-y1);
  }
  __syncthreads();
  int nw = (n + 63) >> 6;
  unsigned long long* rows = gmask + (size_t)c*N_BOX*GNW;
  for (int task = tid; task < rows_here*nw; task += 256){
    int w = task / rows_here, ri = task - w*rows_here;
    int i = r0 + ri;
    float ax1=X1[i], ay1=Y1[i], ax2=X2[i], ay2=Y2[i], areaA=AR[i];
    unsigned long long bits = 0;
    int j0 = w << 6;
    int jb = i+1 > j0 ? i+1 : j0;
    int je = j0+64 < n ? j0+64 : n;
    for (int j = jb; j < je; ++j){
      float iw = fmaxf(1e-10f, fminf(ax2,X2[j]) - fmaxf(ax1,X1[j]));
      float ih = fmaxf(1e-10f, fminf(ay2,Y2[j]) - fmaxf(ay1,Y1[j]));
      float inter = iw*ih;
      float iou = inter / (areaA + AR[j] - inter);
      bits |= (unsigned long long)(iou > 0.5f) << (j - j0);
    }
    rows[(size_t)i*GNW + w] = bits;
  }
}

// ---------------- NMS phase B: word-centric greedy scan, 1 wave per class ----------------
__global__ __launch_bounds__(64) void nmsscan_k(const int* __restrict__ ord,
    const int* __restrict__ cnt, const unsigned long long* __restrict__ gmask,
    float* __restrict__ keep){
  __shared__ int sidx[N_BOX];
  int c = blockIdx.x, lane = threadIdx.x;
  int n = cnt[c];
  if (n <= 0) return;
  int nw = (n + 63) >> 6;
  for (int t = lane; t < n; t += 64) sidx[t] = ord[c*N_BOX + t];
  __syncthreads();
  const unsigned long long* rows = gmask + (size_t)c*N_BOX*GNW;
  bool act = lane < nw;
  unsigned long long S = 0;
  unsigned long long diag = (lane < n) ? rows[(size_t)lane*GNW + 0] : 0ull;
  for (int w = 0; w < nw; ++w){
    int base = w << 6;
    int nb = n - base; if (nb > 64) nb = 64;
    unsigned int slo = (unsigned)__builtin_amdgcn_readlane((int)(unsigned)S, w);
    unsigned int shi = (unsigned)__builtin_amdgcn_readlane((int)(unsigned)(S >> 32), w);
    unsigned long long sup = ((unsigned long long)shi << 32) | slo;
    unsigned long long validm = (nb >= 64) ? ~0ull : ((1ull << nb) - 1ull);
    unsigned long long avail = ~sup & validm;
    unsigned long long kmask = 0;
    unsigned long long diag_next = 0;
    if (w+1 < nw){
      int i2 = base + 64 + lane;
      if (i2 < n) diag_next = rows[(size_t)i2*GNW + (w+1)];
    }
    while (avail){
      int b = __builtin_ctzll(avail);
      kmask |= 1ull << b;
      unsigned int dlo = (unsigned)__builtin_amdgcn_readlane((int)(unsigned)diag, b);
      unsigned int dhi = (unsigned)__builtin_amdgcn_readlane((int)(unsigned)(diag >> 32), b);
      unsigned long long drow = ((unsigned long long)dhi << 32) | dlo;
      sup |= drow;
      avail &= ~(1ull << b);
      avail &= ~sup;
      if (act && lane > w)
        S |= rows[(size_t)(base + b)*GNW + lane];
    }
    if ((kmask >> lane) & 1ull) keep[sidx[base + lane]] = 1.f;
    diag = diag_next;
  }
}

static inline size_t align256(size_t x){ return (x + 255) & ~(size_t)255; }

extern "C" void kernel_launch(void* const* d_in, const int* in_sizes, int n_in,
                              void* d_out, int out_size, void* d_ws, size_t ws_size,
                              hipStream_t stream){
  const float* feat2 = (const float*)d_in[0];   // (512,38,38)
  const float* feat3 = (const float*)d_in[1];   // (1024,19,19)
  const float* w1a = (const float*)d_in[2];
  const float* b1a = (const float*)d_in[3];
  const float* w1b = (const float*)d_in[4];
  const float* b1b = (const float*)d_in[5];
  const float* wr  = (const float*)d_in[6];
  const float* br  = (const float*)d_in[7];
  const float* w2  = (const float*)d_in[8];
  const float* b2  = (const float*)d_in[9];
  const float* wp  = (const float*)d_in[10];
  const float* bp  = (const float*)d_in[11];
  float* out = (float*)d_out;
  char* ws = (char*)d_ws;

  size_t off = 0;
  float* part = (float*)(ws + off); off = align256(off + (size_t)18*1024*NPIX*4);
  f16* wpk  = (f16*)(ws + off); off = align256(off + (size_t)8*360*8192*2);   // 47.2MB: 8x360 tiles x 16KB
  f16* a1h  = (f16*)(ws + off); off = align256(off + (size_t)NPIX*1024*2);
  f16* a1l  = (f16*)(ws + off); off = align256(off + (size_t)NPIX*1024*2);
  f16* a2h  = (f16*)(ws + off); off = align256(off + (size_t)NPIX*1024*2);
  f16* a2l  = (f16*)(ws + off); off = align256(off + (size_t)NPIX*1024*2);
  f16* a3h  = (f16*)(ws + off); off = align256(off + (size_t)NPIX*1024*2);
  f16* a3l  = (f16*)(ws + off); off = align256(off + (size_t)NPIX*1024*2);
  f16* cath = (f16*)(ws + off); off = align256(off + (size_t)NPIX*1280*2);
  f16* catl = (f16*)(ws + off); off = align256(off + (size_t)NPIX*1280*2);
  float* pred = (float*)(ws + off); off = align256(off + (size_t)125*NPIX*4);
  float* wrT  = (float*)(ws + off); off = align256(off + (size_t)512*64*4);
  float* wpT  = (float*)(ws + off); off = align256(off + (size_t)1024*125*4);
  int* cls_i  = (int*)(ws + off); off = align256(off + (size_t)N_BOX*4);
  int* ord    = (int*)(ws + off); off = align256(off + (size_t)NCLS*N_BOX*4);
  int* cnt    = (int*)(ws + off); off = align256(off + (size_t)NCLS*4);
  f16* zpage  = (f16*)(ws + off); off = align256(off + 256);
  unsigned long long* gmask = (unsigned long long*)part;   // part free by NMS time

  transpose_k<<<(64*512 + 255)/256, 256, 0, stream>>>(wr, wrT, 64, 512);
  transpose_k<<<(125*1024 + 255)/256, 256, 0, stream>>>(wp, wpT, 125, 1024);
  act1prep_k<<<(NPIX*1024 + 255)/256, 256, 0, stream>>>(feat3, a1h, a1l, zpage);
  reorg_conv_k<<<361, 256, 0, stream>>>(feat2, wrT, br, cath, catl);

  // conv1: act1 (Cin=1024, NK=288, cpt=32): splitk 16 x chunks 18 -> 384 blocks
  wprep11_k<<<(8*288*1024)/256, 256, 0, stream>>>(w1a, wpk, 1024, 32, 288, 8*288*1024);
  { dim3 g(8, 3, 16);
    conv_mfma_k<<<g, 256, 0, stream>>>(wpk, a1h, a1l, zpage, part, 1024, 18, 32, 288); }
  reduce16v_k<<<(1024*NPIX + 255)/256, 256, 0, stream>>>(part, b1a, a2h, a2l, 1024, 0, 16);

  // conv2: act2 -> cat[256:1280)
  wprep11_k<<<(8*288*1024)/256, 256, 0, stream>>>(w1b, wpk, 1024, 32, 288, 8*288*1024);
  { dim3 g(8, 3, 16);
    conv_mfma_k<<<g, 256, 0, stream>>>(wpk, a2h, a2l, zpage, part, 1024, 18, 32, 288); }
  reduce16v_k<<<(1024*NPIX + 255)/256, 256, 0, stream>>>(part, b1b, cath, catl, 1280, 256, 16);

  // conv3: cat (Cin=1280, NK=360, cpt=40): splitk 18 x chunks 20 -> 432 blocks
  wprep11_k<<<(8*360*1024)/256, 256, 0, stream>>>(w2, wpk, 1280, 40, 360, 8*360*1024);
  { dim3 g(8, 3, 18);
    conv_mfma_k<<<g, 256, 0, stream>>>(wpk, cath, catl, zpage, part, 1280, 20, 40, 360); }
  reduce16v_k<<<(1024*NPIX + 255)/256, 256, 0, stream>>>(part, b2, a3h, a3l, 1024, 0, 18);

  // pred 1x1 + decode + NMS
  pred_conv_k<<<181, 256, 0, stream>>>(a3h, a3l, wpT, bp, pred);
  decode_k<<<8, 256, 0, stream>>>(pred, out, cls_i, cnt);
  rank_k<<<(N_BOX + 3)/4, 256, 0, stream>>>(out + 7220, cls_i, ord, cnt);
  { dim3 mg(NCLS, 8);
    maskbuild_k<<<mg, 256, 0, stream>>>(out, ord, cnt, gmask); }
  nmsscan_k<<<NCLS, 64, 0, stream>>>(ord, cnt, gmask, out + 10830);
}